// Round 1
// baseline (4190.509 us; speedup 1.0000x reference)
//
#include <hip/hip_runtime.h>
#include <math.h>

#define N_NODES 200000
#define N_EDGES 3200000
#define M_SEL   100000
#define NEX     32
#define NT      11
#define CH      32
#define HID     1024
#define NL      8
#define BN_EPS  1e-5f

// ---------------------------------------------------------------------------
// CSR build: histogram -> scan -> scatter
// ---------------------------------------------------------------------------
__global__ void __launch_bounds__(256) hist_kernel(
    const int* __restrict__ src, const int* __restrict__ dst,
    int* __restrict__ deg_in, int* __restrict__ deg_out) {
  int e = blockIdx.x * blockDim.x + threadIdx.x;
  if (e < N_EDGES) {
    atomicAdd(&deg_in[dst[e]], 1);   // in-edges grouped by dst
    atomicAdd(&deg_out[src[e]], 1);  // out-edges grouped by src
  }
}

// Two independent exclusive scans (block 0: in, block 1: out), 1024 threads,
// shfl-based wave scan + 16-wave combine. Writes off[0..N] and cur[i]=off[i].
__global__ void __launch_bounds__(1024) scan_kernel(
    const int* __restrict__ degA, int* __restrict__ offA, int* __restrict__ curA,
    const int* __restrict__ degB, int* __restrict__ offB, int* __restrict__ curB) {
  const int n = N_NODES;
  const int* deg = blockIdx.x ? degB : degA;
  int* off = blockIdx.x ? offB : offA;
  int* cur = blockIdx.x ? curB : curA;
  __shared__ int wsum[16];
  int tid = threadIdx.x;
  int lane = tid & 63, wid = tid >> 6;
  int carry = 0;
  if (tid == 0) off[0] = 0;
  for (int base = 0; base < n; base += 1024) {
    int idx = base + tid;
    int v0 = (idx < n) ? deg[idx] : 0;
    int v = v0;
#pragma unroll
    for (int o = 1; o < 64; o <<= 1) {
      int t = __shfl_up(v, o);
      if (lane >= o) v += t;
    }
    if (lane == 63) wsum[wid] = v;
    __syncthreads();
    if (tid < 16) {
      int t = wsum[tid];
#pragma unroll
      for (int o = 1; o < 16; o <<= 1) {
        int u = __shfl_up(t, o);
        if (tid >= o) t += u;
      }
      wsum[tid] = t;
    }
    __syncthreads();
    int add = carry + (wid ? wsum[wid - 1] : 0);
    int incl = v + add;
    if (idx < n) { off[idx + 1] = incl; cur[idx] = incl - v0; }
    int tot = wsum[15];
    __syncthreads();
    carry += tot;
  }
}

__global__ void __launch_bounds__(256) scatter_kernel(
    const int* __restrict__ src, const int* __restrict__ dst,
    int* __restrict__ cur_in, int* __restrict__ cur_out,
    int* __restrict__ csr_in, int* __restrict__ csr_out) {
  int e = blockIdx.x * blockDim.x + threadIdx.x;
  if (e < N_EDGES) {
    int s = src[e], d = dst[e];
    int p = atomicAdd(&cur_in[d], 1);  csr_in[p] = s;   // sources of in-edges of d
    int q = atomicAdd(&cur_out[s], 1); csr_out[q] = d;  // dsts of out-edges of s
  }
}

// ---------------------------------------------------------------------------
// A0: x0 = emb[nodes]; y = x0 @ [w0_out | w0_back]   (no BN/ReLU)
// ---------------------------------------------------------------------------
__global__ void __launch_bounds__(256) emb_mm_kernel(
    const int* __restrict__ nodes, const float* __restrict__ emb,
    const float* __restrict__ w_out, const float* __restrict__ w_back,
    float* __restrict__ y) {
  __shared__ float W[CH][CH];
  __shared__ float Esh[NT * CH];
  int tid = threadIdx.x;
  for (int t = tid; t < CH * CH; t += blockDim.x) {
    int k = t >> 5, j = t & 31;
    W[k][j] = (j < 16) ? w_out[k * 16 + j] : w_back[k * 16 + j - 16];
  }
  for (int t = tid; t < NT * CH; t += blockDim.x) Esh[t] = emb[t];
  __syncthreads();
  int i = blockIdx.x * blockDim.x + tid;
  if (i >= N_NODES) return;
  int tn = nodes[i];
  float v[CH];
#pragma unroll
  for (int k = 0; k < CH; k++) v[k] = Esh[tn * CH + k];
  float acc[CH];
#pragma unroll
  for (int j = 0; j < CH; j++) acc[j] = 0.f;
#pragma unroll
  for (int k = 0; k < CH; k++) {
    float vk = v[k];
#pragma unroll
    for (int j = 0; j < CH; j++) acc[j] += vk * W[k][j];
  }
  float4* yp = (float4*)(y + (size_t)i * CH);
#pragma unroll
  for (int q = 0; q < 8; q++)
    yp[q] = make_float4(acc[4 * q], acc[4 * q + 1], acc[4 * q + 2], acc[4 * q + 3]);
}

// ---------------------------------------------------------------------------
// A: y = relu(bn(x; stats,g,b)) @ [w_out | w_back]
// stats = [sum(32), sumsq(32)] accumulated by the previous agg kernel.
// ---------------------------------------------------------------------------
__global__ void __launch_bounds__(256) bn_relu_mm_kernel(
    const float* __restrict__ xin, const float* __restrict__ stats,
    const float* __restrict__ gamma, const float* __restrict__ beta,
    const float* __restrict__ w_out, const float* __restrict__ w_back,
    float* __restrict__ y) {
  __shared__ float W[CH][CH];
  __shared__ float sc[CH], sh[CH];
  int tid = threadIdx.x;
  for (int t = tid; t < CH * CH; t += blockDim.x) {
    int k = t >> 5, j = t & 31;
    W[k][j] = (j < 16) ? w_out[k * 16 + j] : w_back[k * 16 + j - 16];
  }
  if (tid < CH) {
    float m  = stats[tid] * (1.0f / N_NODES);
    float s2 = stats[CH + tid] * (1.0f / N_NODES);
    float var = s2 - m * m;
    float scale = gamma[tid] * rsqrtf(var + BN_EPS);
    sc[tid] = scale;
    sh[tid] = beta[tid] - m * scale;
  }
  __syncthreads();
  int i = blockIdx.x * blockDim.x + tid;
  if (i >= N_NODES) return;
  const float4* xp = (const float4*)(xin + (size_t)i * CH);
  float v[CH];
#pragma unroll
  for (int q = 0; q < 8; q++) {
    float4 t = xp[q];
    v[4 * q + 0] = fmaxf(t.x * sc[4 * q + 0] + sh[4 * q + 0], 0.f);
    v[4 * q + 1] = fmaxf(t.y * sc[4 * q + 1] + sh[4 * q + 1], 0.f);
    v[4 * q + 2] = fmaxf(t.z * sc[4 * q + 2] + sh[4 * q + 2], 0.f);
    v[4 * q + 3] = fmaxf(t.w * sc[4 * q + 3] + sh[4 * q + 3], 0.f);
  }
  float acc[CH];
#pragma unroll
  for (int j = 0; j < CH; j++) acc[j] = 0.f;
#pragma unroll
  for (int k = 0; k < CH; k++) {
    float vk = v[k];
#pragma unroll
    for (int j = 0; j < CH; j++) acc[j] += vk * W[k][j];
  }
  float4* yp = (float4*)(y + (size_t)i * CH);
#pragma unroll
  for (int q = 0; q < 8; q++)
    yp[q] = make_float4(acc[4 * q], acc[4 * q + 1], acc[4 * q + 2], acc[4 * q + 3]);
}

// ---------------------------------------------------------------------------
// B: aggregation. Job j<N: out[j][0:16]  = sum_{e in-edges of j}  y[src][0:16]
//    Job j>=N: out[j-N][16:32] = sum_{e out-edges} y[dst][16:32]
// 4 threads (float4 each) per job. Optional residual add, optional
// per-channel sum/sumsq accumulation (for the next BN) via shfl+LDS+atomics.
// N % 16 == 0 -> each wave is direction-uniform.
// ---------------------------------------------------------------------------
__global__ void __launch_bounds__(256) agg_kernel(
    const float* __restrict__ y, const float* __restrict__ xres,
    float* __restrict__ out,
    const int* __restrict__ off_in, const int* __restrict__ csr_in,
    const int* __restrict__ off_out, const int* __restrict__ csr_out,
    float* __restrict__ stats) {
  __shared__ float ssum[CH], sssq[CH];
  int tid = threadIdx.x;
  if (tid < CH) { ssum[tid] = 0.f; sssq[tid] = 0.f; }
  __syncthreads();
  const int total = 8 * N_NODES;  // 2N jobs * 4 threads
  int stride = gridDim.x * blockDim.x;
  for (int t = blockIdx.x * blockDim.x + tid; t < total; t += stride) {
    int q = t & 3;
    int j = t >> 2;
    int half = (j >= N_NODES) ? 1 : 0;
    int i = half ? j - N_NODES : j;
    const int* off = half ? off_out : off_in;
    const int* csr = half ? csr_out : csr_in;
    int lo = off[i], hi = off[i + 1];
    int base = half * 16 + q * 4;
    float4 acc = make_float4(0.f, 0.f, 0.f, 0.f);
    for (int e = lo; e < hi; e++) {
      int nb = csr[e];
      float4 p = *(const float4*)(y + (size_t)nb * CH + base);
      acc.x += p.x; acc.y += p.y; acc.z += p.z; acc.w += p.w;
    }
    if (xres) {
      float4 r = *(const float4*)(xres + (size_t)i * CH + base);
      acc.x += r.x; acc.y += r.y; acc.z += r.z; acc.w += r.w;
    }
    *(float4*)(out + (size_t)i * CH + base) = acc;
    if (stats) {
      float4 sq = make_float4(acc.x * acc.x, acc.y * acc.y, acc.z * acc.z, acc.w * acc.w);
#pragma unroll
      for (int o = 32; o >= 4; o >>= 1) {
        acc.x += __shfl_down(acc.x, o); acc.y += __shfl_down(acc.y, o);
        acc.z += __shfl_down(acc.z, o); acc.w += __shfl_down(acc.w, o);
        sq.x += __shfl_down(sq.x, o);  sq.y += __shfl_down(sq.y, o);
        sq.z += __shfl_down(sq.z, o);  sq.w += __shfl_down(sq.w, o);
      }
      if ((tid & 63) < 4) {  // lanes 0..3 hold per-channel-quad totals of 16 jobs
        atomicAdd(&ssum[base + 0], acc.x); atomicAdd(&ssum[base + 1], acc.y);
        atomicAdd(&ssum[base + 2], acc.z); atomicAdd(&ssum[base + 3], acc.w);
        atomicAdd(&sssq[base + 0], sq.x);  atomicAdd(&sssq[base + 1], sq.y);
        atomicAdd(&sssq[base + 2], sq.z);  atomicAdd(&sssq[base + 3], sq.w);
      }
    }
  }
  if (stats) {
    __syncthreads();
    if (tid < CH) {
      atomicAdd(&stats[tid], ssum[tid]);
      atomicAdd(&stats[CH + tid], sssq[tid]);
    }
  }
}

// ---------------------------------------------------------------------------
// MLP head: s[m] = relu(relu(x[idx]) @ wh + bh) @ wo + bo ; seg[m] = assignment[idx]
// ---------------------------------------------------------------------------
__global__ void __launch_bounds__(256) score_kernel(
    const float* __restrict__ x, const int* __restrict__ indices,
    const int* __restrict__ assignment,
    const float* __restrict__ wh, const float* __restrict__ bh,
    const float* __restrict__ wo, const float* __restrict__ bo,
    float* __restrict__ s, int* __restrict__ seg) {
  __shared__ __align__(16) float s_wh[256][36];  // 36: 16B-aligned row stride
  __shared__ float s_wo[256];
  __shared__ float s_bh[256];
  int tid = threadIdx.x;
  int m = blockIdx.x * 256 + tid;
  bool valid = m < M_SEL;
  float a[CH];
  int idx = 0;
  if (valid) {
    idx = indices[m];
    const float4* xp = (const float4*)(x + (size_t)idx * CH);
#pragma unroll
    for (int q = 0; q < 8; q++) {
      float4 t = xp[q];
      a[4 * q + 0] = fmaxf(t.x, 0.f); a[4 * q + 1] = fmaxf(t.y, 0.f);
      a[4 * q + 2] = fmaxf(t.z, 0.f); a[4 * q + 3] = fmaxf(t.w, 0.f);
    }
  }
  float sacc = 0.f;
  for (int t0 = 0; t0 < HID; t0 += 256) {
    for (int u = tid; u < CH * 256; u += 256) {
      int k = u >> 8, jj = u & 255;
      s_wh[jj][k] = wh[(size_t)k * HID + t0 + jj];
    }
    s_wo[tid] = wo[t0 + tid];
    s_bh[tid] = bh[t0 + tid];
    __syncthreads();
    if (valid) {
      for (int jj = 0; jj < 256; jj++) {
        float h = s_bh[jj];
        const float4* wp = (const float4*)&s_wh[jj][0];
#pragma unroll
        for (int q = 0; q < 8; q++) {
          float4 w = wp[q];
          h += a[4 * q] * w.x + a[4 * q + 1] * w.y + a[4 * q + 2] * w.z + a[4 * q + 3] * w.w;
        }
        sacc += fmaxf(h, 0.f) * s_wo[jj];
      }
    }
    __syncthreads();
  }
  if (valid) {
    s[m] = sacc + bo[0];
    seg[m] = assignment[idx];
  }
}

// ---------------------------------------------------------------------------
// Segmented log-softmax. seg is sorted; one block per segment.
// ---------------------------------------------------------------------------
__device__ __forceinline__ int lower_bound_dev(const int* a, int n, int key) {
  int lo = 0, hi = n;
  while (lo < hi) { int mid = (lo + hi) >> 1; if (a[mid] < key) lo = mid + 1; else hi = mid; }
  return lo;
}

__global__ void __launch_bounds__(256) logsoftmax_kernel(
    const float* __restrict__ s, const int* __restrict__ seg, float* __restrict__ out) {
  __shared__ float red[256];
  __shared__ int bounds[2];
  int tid = threadIdx.x;
  int b = blockIdx.x;
  if (tid == 0) {
    bounds[0] = lower_bound_dev(seg, M_SEL, b);
    bounds[1] = lower_bound_dev(seg, M_SEL, b + 1);
  }
  __syncthreads();
  int lo = bounds[0], hi = bounds[1];
  float mx = -INFINITY;
  for (int i = lo + tid; i < hi; i += 256) mx = fmaxf(mx, s[i]);
  red[tid] = mx; __syncthreads();
  for (int o = 128; o > 0; o >>= 1) { if (tid < o) red[tid] = fmaxf(red[tid], red[tid + o]); __syncthreads(); }
  float mxv = red[0];
  __syncthreads();
  float sum = 0.f;
  for (int i = lo + tid; i < hi; i += 256) sum += expf(s[i] - mxv);
  red[tid] = sum; __syncthreads();
  for (int o = 128; o > 0; o >>= 1) { if (tid < o) red[tid] += red[tid + o]; __syncthreads(); }
  float lse = logf(red[0]);
  for (int i = lo + tid; i < hi; i += 256) out[i] = (s[i] - mxv) - lse;
}

// ---------------------------------------------------------------------------
extern "C" void kernel_launch(void* const* d_in, const int* in_sizes, int n_in,
                              void* d_out, int out_size, void* d_ws, size_t ws_size,
                              hipStream_t stream) {
  const int*   assignment = (const int*)d_in[1];
  const int*   nodes      = (const int*)d_in[2];
  const int*   src        = (const int*)d_in[3];
  const int*   dst        = (const int*)d_in[4];
  const int*   indices    = (const int*)d_in[5];
  const float* emb        = (const float*)d_in[6];
  const float* w0_out     = (const float*)d_in[7];
  const float* w0_back    = (const float*)d_in[8];
  const float* bn1_gamma  = (const float*)d_in[9];
  const float* bn1_beta   = (const float*)d_in[10];
  const float* w1_out     = (const float*)d_in[11];
  const float* w1_back    = (const float*)d_in[12];
  const float* bn2_gamma  = (const float*)d_in[13];
  const float* bn2_beta   = (const float*)d_in[14];
  const float* w2_out     = (const float*)d_in[15];
  const float* w2_back    = (const float*)d_in[16];
  const float* wh         = (const float*)d_in[17];
  const float* bh         = (const float*)d_in[18];
  const float* wo         = (const float*)d_in[19];
  const float* bo         = (const float*)d_in[20];
  float* out = (float*)d_out;

  char* ws = (char*)d_ws;
  size_t off = 0;
  auto alloc = [&](size_t bytes) {
    char* p = ws + off;
    off = (off + bytes + 255) & ~(size_t)255;
    return p;
  };
  int* deg_in  = (int*)alloc((size_t)2 * N_NODES * 4); int* deg_out = deg_in + N_NODES;
  int* cur_in  = (int*)alloc((size_t)2 * N_NODES * 4); int* cur_out = cur_in + N_NODES;
  int* off_in  = (int*)alloc((size_t)(N_NODES + 1) * 4);
  int* off_out = (int*)alloc((size_t)(N_NODES + 1) * 4);
  float* stats = (float*)alloc((size_t)16 * 64 * 4);
  int* csr_in  = (int*)alloc((size_t)N_EDGES * 4);
  int* csr_out = (int*)alloc((size_t)N_EDGES * 4);
  float* xb = (float*)alloc((size_t)N_NODES * CH * 4);
  float* yb = (float*)alloc((size_t)N_NODES * CH * 4);
  float* hb = (float*)alloc((size_t)N_NODES * CH * 4);
  float* sb = (float*)alloc((size_t)M_SEL * 4);
  int* segb = (int*)alloc((size_t)M_SEL * 4);

  hipMemsetAsync(deg_in, 0, (size_t)2 * N_NODES * 4, stream);
  hipMemsetAsync(stats, 0, (size_t)16 * 64 * 4, stream);

  hist_kernel<<<N_EDGES / 256, 256, 0, stream>>>(src, dst, deg_in, deg_out);
  scan_kernel<<<2, 1024, 0, stream>>>(deg_in, off_in, cur_in, deg_out, off_out, cur_out);
  scatter_kernel<<<N_EDGES / 256, 256, 0, stream>>>(src, dst, cur_in, cur_out, csr_in, csr_out);

  const int gA = (N_NODES + 255) / 256;
  emb_mm_kernel<<<gA, 256, 0, stream>>>(nodes, emb, w0_out, w0_back, yb);
  agg_kernel<<<1024, 256, 0, stream>>>(yb, nullptr, xb, off_in, csr_in, off_out, csr_out,
                                       stats + 0 * 64);
  for (int l = 0; l < NL; l++) {
    bn_relu_mm_kernel<<<gA, 256, 0, stream>>>(xb, stats + (2 * l) * 64,
                                              bn1_gamma + l * CH, bn1_beta + l * CH,
                                              w1_out + l * CH * 16, w1_back + l * CH * 16, yb);
    agg_kernel<<<1024, 256, 0, stream>>>(yb, nullptr, hb, off_in, csr_in, off_out, csr_out,
                                         stats + (2 * l + 1) * 64);
    bn_relu_mm_kernel<<<gA, 256, 0, stream>>>(hb, stats + (2 * l + 1) * 64,
                                              bn2_gamma + l * CH, bn2_beta + l * CH,
                                              w2_out + l * CH * 16, w2_back + l * CH * 16, yb);
    agg_kernel<<<1024, 256, 0, stream>>>(yb, xb, xb, off_in, csr_in, off_out, csr_out,
                                         (l < NL - 1) ? (stats + (2 * l + 2) * 64) : nullptr);
  }
  score_kernel<<<(M_SEL + 255) / 256, 256, 0, stream>>>(xb, indices, assignment,
                                                        wh, bh, wo, bo, sb, segb);
  logsoftmax_kernel<<<NEX, 256, 0, stream>>>(sb, segb, out);
}